// Round 8
// baseline (271.376 us; speedup 1.0000x reference)
//
#include <hip/hip_runtime.h>

// DynamicMaskHead fused kernel (v3: scalar weights):
//   x = concat(rel_coords(2), mask_feats[im_ind](8))  -> 10ch
//   h0 = relu(W0(8x10) x + b0); h1 = relu(W1(8x8) h0 + b1); logit = W2(1x8) h1 + b2
//   out = aligned_bilinear(logits, factor=2)  (upsample, shift-by-1, crop)
//
// v3 vs v2: weights read DIRECTLY from params[] with block-uniform indices ->
// compiler emits s_load (SGPRs, scalar cache). v1/v2 staged them in LDS: ~169
// broadcast ds_read_b32 per thread on the one-per-CU LDS pipe was the real
// bottleneck (v2's occupancy fix was neutral -> not latency-bound).
// Per-px sequential layers (xf/h0/h1 live ranges overlap) keeps VGPRs low
// without cross-px weight amortization (SGPR reads are free).
// Logits tile lives in LDS; never hits HBM.

#define HH   128
#define WW   192
#define OHH  256
#define OWW  384
#define THY  32          // output tile height
#define TWX  128         // output tile width
#define LR   18          // logits tile rows = THY/2 + 2
#define LC   66          // logits tile cols = TWX/2 + 2 (logical)
#define LCP  67          // padded row stride (odd -> bank-friendly)
#define NPX  (LR*LC)     // 1188
#define NPARAMS 169

__global__ __launch_bounds__(256, 6)
void dmh_fused(const float* __restrict__ mask_feats,
               const float* __restrict__ params,
               const float* __restrict__ locs,
               const int*   __restrict__ im_inds,
               const int*   __restrict__ fpn,
               float* __restrict__ out)
{
    __shared__ float L[LR][LCP];

    const int inst = blockIdx.z;
    const int tid  = threadIdx.x;

    // Block-uniform weight base: all w[] accesses below have compile-time
    // offsets -> uniform -> s_load into SGPRs (no LDS, no VALU).
    const float* __restrict__ w = params + (size_t)inst * NPARAMS;

    const int   im     = im_inds[inst];
    const float instx  = locs[2*inst];
    const float insty  = locs[2*inst + 1];
    const float invsoi = 1.0f / (float)(64 << fpn[inst]);   // SOI = 64<<lvl (exact pow2)

    const int oy0 = blockIdx.y * THY;
    const int ox0 = blockIdx.x * TWX;
    const int r0  = oy0 >> 1;
    const int c0  = ox0 >> 1;

    const float* __restrict__ fbase = mask_feats + (size_t)im * 8 * HH * WW;

    // ---- phase 1: logits tile, per-px sequential MLP (5 px / thread) ----
#pragma unroll 2
    for (int k = 0; k < 5; ++k) {
        int p = tid + 256*k;
        if (p > NPX-1) p = NPX-1;      // tail threads recompute last px (benign dup store)
        int lr = p / LC;
        int lc = p - lr*LC;
        int gy = r0 - 1 + lr; gy = gy < 0 ? 0 : (gy > HH-1 ? HH-1 : gy);
        int gx = c0 - 1 + lc; gx = gx < 0 ? 0 : (gx > WW-1 ? WW-1 : gx);
        const float rx = (instx - (float)(gx*8 + 4)) * invsoi;
        const float ry = (insty - (float)(gy*8 + 4)) * invsoi;
        const float* fp = fbase + gy*WW + gx;

        float xf[8];
#pragma unroll
        for (int c = 0; c < 8; ++c) xf[c] = fp[c*HH*WW];

        float h0[8];
#pragma unroll
        for (int o = 0; o < 8; ++o) {
            float a = w[o*10]*rx + w[o*10 + 1]*ry;
#pragma unroll
            for (int c = 0; c < 8; ++c) a += w[o*10 + 2 + c]*xf[c];
            h0[o] = fmaxf(a + w[152 + o], 0.0f);
        }

        float h1[8];
#pragma unroll
        for (int o = 0; o < 8; ++o) {
            float a = w[80 + o*8]*h0[0];
#pragma unroll
            for (int i = 1; i < 8; ++i) a += w[80 + o*8 + i]*h0[i];
            h1[o] = fmaxf(a + w[160 + o], 0.0f);
        }

        float a = w[144]*h1[0];
#pragma unroll
        for (int i = 1; i < 8; ++i) a += w[144 + i]*h1[i];
        L[lr][lc] = a + w[168];
    }

    __syncthreads();

    // ---- phase 2: aligned bilinear 2x, float4 stores ----
    // thread -> 4 consecutive x outputs; even base xb=2m needs logits cols m-1..m+2
    float* __restrict__ obase = out + (size_t)inst * OHH * OWW;
#pragma unroll
    for (int j = 0; j < 4; ++j) {
        const int yl = (tid >> 5) + 8*j;
        const int xq = (tid & 31) * 4;
        const int y  = oy0 + yl;
        const int yy = (y > 0) ? (y - 1) : 0;
        const int iy0 = yy >> 1;
        const float fy = (yy & 1) ? 0.5f : 0.0f;
        const float gy1 = 1.0f - fy;
        const int ly = iy0 - r0 + 1;       // row iy0 lives at LDS row iy0-(r0-1)
        const int lx = xq >> 1;            // LDS col of global logits col m-1
        float t[3];
#pragma unroll
        for (int i = 0; i < 3; ++i) {
            const float a  = L[ly  ][lx + i];
            const float bb = L[ly+1][lx + i];
            t[i] = a*gy1 + bb*fy;          // rows first (matches reference axis order)
        }
        float4 r;
        r.x = 0.5f*t[0] + 0.5f*t[1];   // x even  : fx=0.5 between cols m-1,m
        r.y = t[1];                    // x odd   : fx=0, col m
        r.z = 0.5f*t[1] + 0.5f*t[2];   // x even  : cols m,m+1
        r.w = t[2];                    // x odd   : col m+1
        *(float4*)(obase + (size_t)y*OWW + ox0 + xq) = r;
    }
}

extern "C" void kernel_launch(void* const* d_in, const int* in_sizes, int n_in,
                              void* d_out, int out_size, void* d_ws, size_t ws_size,
                              hipStream_t stream) {
    const float* mask_feats = (const float*)d_in[0];
    const float* params     = (const float*)d_in[1];
    const float* locs       = (const float*)d_in[2];
    const int*   im_inds    = (const int*)d_in[3];
    const int*   fpn        = (const int*)d_in[4];
    float*       out        = (float*)d_out;

    const int n_inst = in_sizes[1] / NPARAMS;   // 400
    dim3 grid(OWW/TWX, OHH/THY, n_inst);        // (3, 8, 400)
    dmh_fused<<<grid, 256, 0, stream>>>(mask_feats, params, locs, im_inds, fpn, out);
}

// Round 9
// 196.447 us; speedup vs baseline: 1.3814x; 1.3814x over previous
//
#include <hip/hip_runtime.h>

// DynamicMaskHead fused kernel (v4: LDS weights, vectorized reads):
//   x = concat(rel_coords(2), mask_feats[im_ind](8))  -> 10ch
//   h0 = relu(W0(8x10) x + b0); h1 = relu(W1(8x8) h0 + b1); logit = W2(1x8) h1 + b2
//   out = aligned_bilinear(logits, factor=2)
//
// History: v1 (LDS weights, 169 ds_read_b32/thread) = 106us. v2 (+occupancy) = 112us
// -> not occupancy-bound. v3 (scalar s_load weights, per-px re-reads) = 157us,
// VGPR=24, VALUBusy 89% -> compiler starved ILP, 4x VALU bloat. v4 returns to the
// v1 structure but cuts LDS weight insts 169->~59 via aligned float4 reads of a
// re-laid-out LDS weight block (W0 rows padded to 12 floats for 16B alignment),
// and keeps VGPRs high (launch_bounds(256,3)) so all 5 px pipeline.
// Logits tile lives in LDS; never hits HBM.

#define HH   128
#define WW   192
#define OHH  256
#define OWW  384
#define THY  32          // output tile height
#define TWX  128         // output tile width
#define LR   18          // logits tile rows = THY/2 + 2
#define LC   66          // logits tile cols = TWX/2 + 2 (logical)
#define LCP  67          // padded row stride
#define NPX  (LR*LC)     // 1188
#define NPARAMS 169
#define PXT  5           // px per thread

__global__ __launch_bounds__(256, 3)
void dmh_fused(const float* __restrict__ mask_feats,
               const float* __restrict__ params,
               const float* __restrict__ locs,
               const int*   __restrict__ im_inds,
               const int*   __restrict__ fpn,
               float* __restrict__ out)
{
    // LDS weight layout (re-mapped for 16B-aligned float4 reads):
    //  W0: 8 rows x 12 (10 used + 2 pad)  [0..96)
    //  W1: 8 rows x 8                     [96..160)
    //  W2: 8                              [160..168)
    //  b0: 8 [168..176)  b1: 8 [176..184) b2: 1 [184]
    __shared__ float sw[192];
    __shared__ float L[LR][LCP];

    const int inst = blockIdx.z;
    const int tid  = threadIdx.x;

    if (tid < NPARAMS) {
        const float v = params[(size_t)inst * NPARAMS + tid];
        int d;
        if      (tid <  80) d = (tid/10)*12 + (tid%10);
        else if (tid < 144) d = 96  + (tid - 80);
        else if (tid < 152) d = 160 + (tid - 144);
        else                d = 168 + (tid - 152);
        sw[d] = v;
    }

    const int   im     = im_inds[inst];
    const float instx  = locs[2*inst];
    const float insty  = locs[2*inst + 1];
    const float invsoi = 1.0f / (float)(64 << fpn[inst]);   // SOI = 64<<lvl (exact pow2)

    const int oy0 = blockIdx.y * THY;
    const int ox0 = blockIdx.x * TWX;
    const int r0  = oy0 >> 1;
    const int c0  = ox0 >> 1;

    __syncthreads();

    const float* __restrict__ fbase = mask_feats + (size_t)im * 8 * HH * WW;

    // ---- phase 1a: gather inputs for all PXT px (loads batched, in flight) ----
    float xf[PXT][8];
    float rx[PXT], ry[PXT];
    int   pix[PXT];
#pragma unroll
    for (int k = 0; k < PXT; ++k) {
        int p = tid + 256*k;
        if (p > NPX-1) p = NPX-1;      // tail threads recompute last px (benign dup store)
        int lr = p / LC;
        int lc = p - lr*LC;
        pix[k] = lr*LCP + lc;
        int gy = r0 - 1 + lr; gy = gy < 0 ? 0 : (gy > HH-1 ? HH-1 : gy);
        int gx = c0 - 1 + lc; gx = gx < 0 ? 0 : (gx > WW-1 ? WW-1 : gx);
        rx[k] = (instx - (float)(gx*8 + 4)) * invsoi;
        ry[k] = (insty - (float)(gy*8 + 4)) * invsoi;
        const float* fp = fbase + gy*WW + gx;
#pragma unroll
        for (int c = 0; c < 8; ++c)
            xf[k][c] = fp[c*HH*WW];
    }

    // ---- layer 0: 8 <- 10, relu; float4 weight reads, amortized over PXT px ----
    float h0[PXT][8];
#pragma unroll
    for (int o = 0; o < 8; ++o) {
        const float4 A = *(const float4*)&sw[12*o];       // wx, wy, c0, c1
        const float4 B = *(const float4*)&sw[12*o + 4];   // c2..c5
        const float2 C = *(const float2*)&sw[12*o + 8];   // c6, c7
        const float  b = sw[168 + o];
#pragma unroll
        for (int k = 0; k < PXT; ++k) {
            float a = A.x*rx[k] + A.y*ry[k]
                    + A.z*xf[k][0] + A.w*xf[k][1]
                    + B.x*xf[k][2] + B.y*xf[k][3]
                    + B.z*xf[k][4] + B.w*xf[k][5]
                    + C.x*xf[k][6] + C.y*xf[k][7];
            h0[k][o] = fmaxf(a + b, 0.0f);
        }
    }

    // ---- layer 1: 8 <- 8, relu ----
    float h1[PXT][8];
#pragma unroll
    for (int o = 0; o < 8; ++o) {
        const float4 A = *(const float4*)&sw[96 + 8*o];
        const float4 B = *(const float4*)&sw[96 + 8*o + 4];
        const float  b = sw[176 + o];
#pragma unroll
        for (int k = 0; k < PXT; ++k) {
            float a = A.x*h0[k][0] + A.y*h0[k][1] + A.z*h0[k][2] + A.w*h0[k][3]
                    + B.x*h0[k][4] + B.y*h0[k][5] + B.z*h0[k][6] + B.w*h0[k][7];
            h1[k][o] = fmaxf(a + b, 0.0f);
        }
    }

    // ---- layer 2: 1 <- 8, store logits tile ----
    {
        const float4 A = *(const float4*)&sw[160];
        const float4 B = *(const float4*)&sw[164];
        const float  b = sw[184];
#pragma unroll
        for (int k = 0; k < PXT; ++k) {
            float a = A.x*h1[k][0] + A.y*h1[k][1] + A.z*h1[k][2] + A.w*h1[k][3]
                    + B.x*h1[k][4] + B.y*h1[k][5] + B.z*h1[k][6] + B.w*h1[k][7];
            ((float*)L)[pix[k]] = a + b;
        }
    }

    __syncthreads();

    // ---- phase 2: aligned bilinear 2x, float4 stores ----
    float* __restrict__ obase = out + (size_t)inst * OHH * OWW;
#pragma unroll
    for (int j = 0; j < 4; ++j) {
        const int yl = (tid >> 5) + 8*j;
        const int xq = (tid & 31) * 4;
        const int y  = oy0 + yl;
        const int yy = (y > 0) ? (y - 1) : 0;
        const int iy0 = yy >> 1;
        const float fy = (yy & 1) ? 0.5f : 0.0f;
        const float gy1 = 1.0f - fy;
        const int ly = iy0 - r0 + 1;       // row iy0 lives at LDS row iy0-(r0-1)
        const int lx = xq >> 1;            // LDS col of global logits col m-1
        float t[3];
#pragma unroll
        for (int i = 0; i < 3; ++i) {
            const float a  = L[ly  ][lx + i];
            const float bb = L[ly+1][lx + i];
            t[i] = a*gy1 + bb*fy;          // rows first (matches reference axis order)
        }
        float4 r;
        r.x = 0.5f*t[0] + 0.5f*t[1];   // x even  : fx=0.5 between cols m-1,m
        r.y = t[1];                    // x odd   : fx=0, col m
        r.z = 0.5f*t[1] + 0.5f*t[2];   // x even  : cols m,m+1
        r.w = t[2];                    // x odd   : col m+1
        *(float4*)(obase + (size_t)y*OWW + ox0 + xq) = r;
    }
}

extern "C" void kernel_launch(void* const* d_in, const int* in_sizes, int n_in,
                              void* d_out, int out_size, void* d_ws, size_t ws_size,
                              hipStream_t stream) {
    const float* mask_feats = (const float*)d_in[0];
    const float* params     = (const float*)d_in[1];
    const float* locs       = (const float*)d_in[2];
    const int*   im_inds    = (const int*)d_in[3];
    const int*   fpn        = (const int*)d_in[4];
    float*       out        = (float*)d_out;

    const int n_inst = in_sizes[1] / NPARAMS;   // 400
    dim3 grid(OWW/TWX, OHH/THY, n_inst);        // (3, 8, 400)
    dmh_fused<<<grid, 256, 0, stream>>>(mask_feats, params, locs, im_inds, fpn, out);
}